// Round 1
// baseline (10269.189 us; speedup 1.0000x reference)
//
#include <hip/hip_runtime.h>
#include <stdint.h>

// ---------------------------------------------------------------------------
// EnhancedSNNCifar: T=8 SNN forward.
//   conv1(3->32,32x32) BN LIF            [T-invariant conv: computed for N only]
//   conv2(32->32,32x32) BN LIF pool->16
//   conv3(32->64,16x16) BN LIF
//   conv4(64->64,16x16) BN LIF pool->8
//   conv5(64->128,8x8) BN LIF
//   conv6(128->128,8x8) BN LIF pool->4
//   fc1(2048->128) LIF ; fc2(128->10) LIF ; mean over T
// Spikes stored as uint8 {0,1}. BN is training-mode over merged T*N batch.
// ---------------------------------------------------------------------------

#define T_STEPS 8
#define NBATCH 128

__global__ void zero_kernel(float* p, int n) {
    int i = blockIdx.x * blockDim.x + threadIdx.x;
    if (i < n) p[i] = 0.0f;
}

// Direct 3x3 pad-1 conv. grid = (M, Cout), block = min(HW,256).
// Writes y[(m*Cout+co)*HW + p] and accumulates per-channel sum/sumsq.
template <typename Tin>
__global__ void conv3x3_kernel(const Tin* __restrict__ in,
                               const float* __restrict__ wgt,
                               const float* __restrict__ bias,
                               float* __restrict__ y,
                               float* __restrict__ ssum,
                               float* __restrict__ ssq,
                               int Cin, int H, int W) {
    const int m  = blockIdx.x;
    const int co = blockIdx.y;
    const int Cout = gridDim.y;
    const int HW = H * W;

    const float* wco = wgt + (size_t)co * Cin * 9;
    const float bv = bias[co];

    float lsum = 0.0f, lsq = 0.0f;

    for (int p = threadIdx.x; p < HW; p += blockDim.x) {
        const int hy = p / W;
        const int wx = p - hy * W;
        float acc = bv;
        for (int ci = 0; ci < Cin; ++ci) {
            const Tin* inc = in + ((size_t)m * Cin + ci) * HW;
            const float* wc = wco + ci * 9;
#pragma unroll
            for (int ky = 0; ky < 3; ++ky) {
                const int iy = hy + ky - 1;
                if (iy < 0 || iy >= H) continue;
#pragma unroll
                for (int kx = 0; kx < 3; ++kx) {
                    const int ix = wx + kx - 1;
                    if (ix < 0 || ix >= W) continue;
                    acc += (float)inc[iy * W + ix] * wc[ky * 3 + kx];
                }
            }
        }
        y[((size_t)m * Cout + co) * HW + p] = acc;
        lsum += acc;
        lsq += acc * acc;
    }

    // block reduction (blockDim.x is a power of two <= 256)
    __shared__ float r1[256];
    __shared__ float r2[256];
    const int tid = threadIdx.x;
    r1[tid] = lsum;
    r2[tid] = lsq;
    __syncthreads();
    for (int s = blockDim.x >> 1; s > 0; s >>= 1) {
        if (tid < s) {
            r1[tid] += r1[tid + s];
            r2[tid] += r2[tid + s];
        }
        __syncthreads();
    }
    if (tid == 0) {
        atomicAdd(&ssum[co], r1[0]);
        atomicAdd(&ssq[co], r2[0]);
    }
}

// Layer-1 BN+LIF: y is [N,C,HW] (same for every t). Emits spikes for all T.
__global__ void bnlif1_kernel(const float* __restrict__ y,
                              const float* __restrict__ ssum,
                              const float* __restrict__ ssq,
                              const float* __restrict__ g,
                              const float* __restrict__ be,
                              uint8_t* __restrict__ s,
                              int C, int HW, float invM) {
    const size_t total = (size_t)NBATCH * C * HW;
    const size_t i = (size_t)blockIdx.x * blockDim.x + threadIdx.x;
    if (i >= total) return;
    const int c = (int)((i / HW) % C);
    const float m = ssum[c] * invM;
    const float var = ssq[c] * invM - m * m;
    const float inv = g[c] / sqrtf(var + 1e-5f);
    const float z = y[i] * inv + (be[c] - m * inv);
    float v = 0.0f;
#pragma unroll
    for (int t = 0; t < T_STEPS; ++t) {
        v += (z - v) * 0.5f;
        const float sp = (v >= 1.0f) ? 1.0f : 0.0f;
        s[(size_t)t * total + i] = (uint8_t)sp;
        v *= (1.0f - sp);
    }
}

// BN+LIF (no pool): y [T*N, C, HW] -> spikes same layout.
__global__ void bnlif_kernel(const float* __restrict__ y,
                             const float* __restrict__ ssum,
                             const float* __restrict__ ssq,
                             const float* __restrict__ g,
                             const float* __restrict__ be,
                             uint8_t* __restrict__ s,
                             int C, int HW, float invM) {
    const size_t total = (size_t)NBATCH * C * HW;  // per-timestep elements
    const size_t i = (size_t)blockIdx.x * blockDim.x + threadIdx.x;
    if (i >= total) return;
    const int c = (int)((i / HW) % C);
    const float m = ssum[c] * invM;
    const float var = ssq[c] * invM - m * m;
    const float inv = g[c] / sqrtf(var + 1e-5f);
    const float sh = be[c] - m * inv;
    float v = 0.0f;
#pragma unroll
    for (int t = 0; t < T_STEPS; ++t) {
        const float z = y[(size_t)t * total + i] * inv + sh;
        v += (z - v) * 0.5f;
        const float sp = (v >= 1.0f) ? 1.0f : 0.0f;
        s[(size_t)t * total + i] = (uint8_t)sp;
        v *= (1.0f - sp);
    }
}

// BN+LIF fused with 2x2 max-pool (OR of binary spikes).
// y [T*N, C, H, W] -> pooled spikes [T, N, C, H/2, W/2].
__global__ void bnlifpool_kernel(const float* __restrict__ y,
                                 const float* __restrict__ ssum,
                                 const float* __restrict__ ssq,
                                 const float* __restrict__ g,
                                 const float* __restrict__ be,
                                 uint8_t* __restrict__ p,
                                 int C, int H, int W, float invM) {
    const int PH = H >> 1, PW = W >> 1;
    const size_t ptotal = (size_t)NBATCH * C * PH * PW;  // per-timestep pooled
    const size_t i = (size_t)blockIdx.x * blockDim.x + threadIdx.x;
    if (i >= ptotal) return;
    const int pw = (int)(i % PW);
    const int ph = (int)((i / PW) % PH);
    const int c = (int)((i / ((size_t)PW * PH)) % C);
    const int n = (int)(i / ((size_t)PW * PH * C));

    const float m = ssum[c] * invM;
    const float var = ssq[c] * invM - m * m;
    const float inv = g[c] / sqrtf(var + 1e-5f);
    const float sh = be[c] - m * inv;

    const size_t ystride = (size_t)NBATCH * C * H * W;
    const size_t base = (((size_t)n * C + c) * H + 2 * ph) * W + 2 * pw;

    float v00 = 0.f, v01 = 0.f, v10 = 0.f, v11 = 0.f;
#pragma unroll
    for (int t = 0; t < T_STEPS; ++t) {
        const float* yt = y + (size_t)t * ystride + base;
        const float z00 = yt[0] * inv + sh;
        const float z01 = yt[1] * inv + sh;
        const float z10 = yt[W] * inv + sh;
        const float z11 = yt[W + 1] * inv + sh;
        v00 += (z00 - v00) * 0.5f;
        v01 += (z01 - v01) * 0.5f;
        v10 += (z10 - v10) * 0.5f;
        v11 += (z11 - v11) * 0.5f;
        const float s00 = (v00 >= 1.0f) ? 1.0f : 0.0f;
        const float s01 = (v01 >= 1.0f) ? 1.0f : 0.0f;
        const float s10 = (v10 >= 1.0f) ? 1.0f : 0.0f;
        const float s11 = (v11 >= 1.0f) ? 1.0f : 0.0f;
        v00 *= (1.0f - s00);
        v01 *= (1.0f - s01);
        v10 *= (1.0f - s10);
        v11 *= (1.0f - s11);
        const float mx = fmaxf(fmaxf(s00, s01), fmaxf(s10, s11));
        p[(size_t)t * ptotal + i] = (uint8_t)mx;
    }
}

// fc1: f [T*N, 2048] uint8, w [128,2048] -> h [T*N,128]
__global__ void fc1_kernel(const uint8_t* __restrict__ f,
                           const float* __restrict__ w,
                           const float* __restrict__ b,
                           float* __restrict__ h) {
    __shared__ float fs[2048];
    const int r = blockIdx.x;  // row = t*N+n
    const uint8_t* fr = f + (size_t)r * 2048;
    for (int i = threadIdx.x; i < 2048; i += blockDim.x)
        fs[i] = (float)fr[i];
    __syncthreads();
    const int o = threadIdx.x;  // blockDim = 128
    const float4* fv = (const float4*)fs;
    const float4* wv = (const float4*)(w + (size_t)o * 2048);
    float acc = b[o];
    for (int i = 0; i < 512; ++i) {
        const float4 a = fv[i];
        const float4 ww = wv[i];
        acc += a.x * ww.x + a.y * ww.y + a.z * ww.z + a.w * ww.w;
    }
    h[(size_t)r * 128 + o] = acc;
}

// LIF over T for fc1 outputs: h [T, NF] -> spikes uint8 same layout.
__global__ void lif_fc_kernel(const float* __restrict__ h,
                              uint8_t* __restrict__ s, int NF) {
    const int i = blockIdx.x * blockDim.x + threadIdx.x;
    if (i >= NF) return;
    float v = 0.0f;
#pragma unroll
    for (int t = 0; t < T_STEPS; ++t) {
        const float z = h[(size_t)t * NF + i];
        v += (z - v) * 0.5f;
        const float sp = (v >= 1.0f) ? 1.0f : 0.0f;
        s[(size_t)t * NF + i] = (uint8_t)sp;
        v *= (1.0f - sp);
    }
}

// fc2 + LIF + mean over T. sh [T,N,128] uint8, w [10,128]. out [N,10].
__global__ void fc2_kernel(const uint8_t* __restrict__ sh,
                           const float* __restrict__ w,
                           const float* __restrict__ b,
                           float* __restrict__ out) {
    const int i = blockIdx.x * blockDim.x + threadIdx.x;
    if (i >= NBATCH * 10) return;
    const int k = i % 10;
    const int n = i / 10;
    float v = 0.0f, acc = 0.0f;
    for (int t = 0; t < T_STEPS; ++t) {
        const uint8_t* row = sh + ((size_t)t * NBATCH + n) * 128;
        float z = b[k];
        for (int o = 0; o < 128; ++o)
            z += (float)row[o] * w[k * 128 + o];
        v += (z - v) * 0.5f;
        const float sp = (v >= 1.0f) ? 1.0f : 0.0f;
        acc += sp;
        v *= (1.0f - sp);
    }
    out[i] = acc * (1.0f / T_STEPS);
}

extern "C" void kernel_launch(void* const* d_in, const int* in_sizes, int n_in,
                              void* d_out, int out_size, void* d_ws, size_t ws_size,
                              hipStream_t stream) {
    const float* x   = (const float*)d_in[0];
    const float* W1  = (const float*)d_in[1];
    const float* Bi1 = (const float*)d_in[2];
    const float* G1  = (const float*)d_in[3];
    const float* BE1 = (const float*)d_in[4];
    const float* W2  = (const float*)d_in[5];
    const float* Bi2 = (const float*)d_in[6];
    const float* G2  = (const float*)d_in[7];
    const float* BE2 = (const float*)d_in[8];
    const float* W3  = (const float*)d_in[9];
    const float* Bi3 = (const float*)d_in[10];
    const float* G3  = (const float*)d_in[11];
    const float* BE3 = (const float*)d_in[12];
    const float* W4  = (const float*)d_in[13];
    const float* Bi4 = (const float*)d_in[14];
    const float* G4  = (const float*)d_in[15];
    const float* BE4 = (const float*)d_in[16];
    const float* W5  = (const float*)d_in[17];
    const float* Bi5 = (const float*)d_in[18];
    const float* G5  = (const float*)d_in[19];
    const float* BE5 = (const float*)d_in[20];
    const float* W6  = (const float*)d_in[21];
    const float* Bi6 = (const float*)d_in[22];
    const float* G6  = (const float*)d_in[23];
    const float* BE6 = (const float*)d_in[24];
    const float* FC1W = (const float*)d_in[25];
    const float* FC1B = (const float*)d_in[26];
    const float* FC2W = (const float*)d_in[27];
    const float* FC2B = (const float*)d_in[28];

    // workspace layout
    uint8_t* ws = (uint8_t*)d_ws;
    float*   Y     = (float*)ws;                       // 134,217,728 B (max y: layer2)
    uint8_t* A     = ws + 134217728;                   // 33,554,432 B spike ping
    uint8_t* Bb    = A + 33554432;                     //  8,388,608 B spike pong
    float*   stats = (float*)(Bb + 8388608);           //  6,144 B (6 layers x 256 floats)
    float*   h     = (float*)((uint8_t*)stats + 8192); //  524,288 B fc1 out
    uint8_t* sh    = (uint8_t*)h + 524288;             //  131,072 B fc1 spikes

    zero_kernel<<<(1536 + 255) / 256, 256, 0, stream>>>(stats, 1536);

    const int TN = T_STEPS * NBATCH;  // 1024

    // ---- layer 1: conv(3->32) over N only (T-invariant), BN, LIF ----
    {
        dim3 g(NBATCH, 32);
        conv3x3_kernel<float><<<g, 256, 0, stream>>>(x, W1, Bi1, Y,
                                                     stats + 0, stats + 128, 3, 32, 32);
        const int total = NBATCH * 32 * 1024;  // 4,194,304
        bnlif1_kernel<<<total / 256, 256, 0, stream>>>(Y, stats + 0, stats + 128,
                                                       G1, BE1, A, 32, 1024,
                                                       1.0f / 131072.0f);
    }
    // ---- layer 2: conv(32->32) 32x32, BN, LIF, pool -> Bb [T,N,32,16,16] ----
    {
        dim3 g(TN, 32);
        conv3x3_kernel<uint8_t><<<g, 256, 0, stream>>>(A, W2, Bi2, Y,
                                                       stats + 256, stats + 384, 32, 32, 32);
        const int ptotal = NBATCH * 32 * 256;  // 1,048,576
        bnlifpool_kernel<<<ptotal / 256, 256, 0, stream>>>(Y, stats + 256, stats + 384,
                                                           G2, BE2, Bb, 32, 32, 32,
                                                           1.0f / (1024.0f * 1024.0f));
    }
    // ---- layer 3: conv(32->64) 16x16, BN, LIF -> A ----
    {
        dim3 g(TN, 64);
        conv3x3_kernel<uint8_t><<<g, 256, 0, stream>>>(Bb, W3, Bi3, Y,
                                                       stats + 512, stats + 640, 32, 16, 16);
        const int total = NBATCH * 64 * 256;  // 2,097,152
        bnlif_kernel<<<total / 256, 256, 0, stream>>>(Y, stats + 512, stats + 640,
                                                      G3, BE3, A, 64, 256,
                                                      1.0f / (1024.0f * 256.0f));
    }
    // ---- layer 4: conv(64->64) 16x16, BN, LIF, pool -> Bb [T,N,64,8,8] ----
    {
        dim3 g(TN, 64);
        conv3x3_kernel<uint8_t><<<g, 256, 0, stream>>>(A, W4, Bi4, Y,
                                                       stats + 768, stats + 896, 64, 16, 16);
        const int ptotal = NBATCH * 64 * 64;  // 524,288
        bnlifpool_kernel<<<ptotal / 256, 256, 0, stream>>>(Y, stats + 768, stats + 896,
                                                           G4, BE4, Bb, 64, 16, 16,
                                                           1.0f / (1024.0f * 256.0f));
    }
    // ---- layer 5: conv(64->128) 8x8, BN, LIF -> A ----
    {
        dim3 g(TN, 128);
        conv3x3_kernel<uint8_t><<<g, 64, 0, stream>>>(Bb, W5, Bi5, Y,
                                                      stats + 1024, stats + 1152, 64, 8, 8);
        const int total = NBATCH * 128 * 64;  // 1,048,576
        bnlif_kernel<<<total / 256, 256, 0, stream>>>(Y, stats + 1024, stats + 1152,
                                                      G5, BE5, A, 128, 64,
                                                      1.0f / (1024.0f * 64.0f));
    }
    // ---- layer 6: conv(128->128) 8x8, BN, LIF, pool -> Bb [T,N,128,4,4] ----
    {
        dim3 g(TN, 128);
        conv3x3_kernel<uint8_t><<<g, 64, 0, stream>>>(A, W6, Bi6, Y,
                                                      stats + 1280, stats + 1408, 128, 8, 8);
        const int ptotal = NBATCH * 128 * 16;  // 262,144
        bnlifpool_kernel<<<ptotal / 256, 256, 0, stream>>>(Y, stats + 1280, stats + 1408,
                                                           G6, BE6, Bb, 128, 8, 8,
                                                           1.0f / (1024.0f * 64.0f));
    }
    // ---- fc1 (2048->128) + LIF ----
    fc1_kernel<<<TN, 128, 0, stream>>>(Bb, FC1W, FC1B, h);
    lif_fc_kernel<<<(NBATCH * 128 + 255) / 256, 256, 0, stream>>>(h, sh, NBATCH * 128);
    // ---- fc2 (128->10) + LIF + mean ----
    fc2_kernel<<<(NBATCH * 10 + 255) / 256, 256, 0, stream>>>(sh, FC2W, FC2B, (float*)d_out);
}

// Round 2
// 1942.287 us; speedup vs baseline: 5.2872x; 5.2872x over previous
//
#include <hip/hip_runtime.h>
#include <stdint.h>

// ---------------------------------------------------------------------------
// EnhancedSNNCifar: T=8 SNN forward.
//   conv1(3->32,32x32) BN LIF            [T-invariant conv: computed for N only]
//   conv2(32->32,32x32) BN LIF pool->16
//   conv3(32->64,16x16) BN LIF
//   conv4(64->64,16x16) BN LIF pool->8
//   conv5(64->128,8x8) BN LIF
//   conv6(128->128,8x8) BN LIF pool->4
//   fc1(2048->128) LIF ; fc2(128->10) LIF ; mean over T
// Spikes stored as uint8 {0,1}. BN is training-mode over merged T*N batch.
//
// R2: spike convs rewritten as LDS-tiled register-blocked direct conv
//     (zeroed-halo spike tile + [ci][k][co] weight tile in LDS; each thread
//      owns 4 pixels x 8 cout fp32 accumulators). fp32 throughout.
// ---------------------------------------------------------------------------

#define T_STEPS 8
#define NBATCH 128

__global__ void zero_kernel(float* p, int n) {
    int i = blockIdx.x * blockDim.x + threadIdx.x;
    if (i < n) p[i] = 0.0f;
}

// Direct 3x3 pad-1 conv (used only for conv1: Cin=3, fp32 input, M=128).
template <typename Tin>
__global__ void conv3x3_kernel(const Tin* __restrict__ in,
                               const float* __restrict__ wgt,
                               const float* __restrict__ bias,
                               float* __restrict__ y,
                               float* __restrict__ ssum,
                               float* __restrict__ ssq,
                               int Cin, int H, int W) {
    const int m  = blockIdx.x;
    const int co = blockIdx.y;
    const int Cout = gridDim.y;
    const int HW = H * W;

    const float* wco = wgt + (size_t)co * Cin * 9;
    const float bv = bias[co];

    float lsum = 0.0f, lsq = 0.0f;

    for (int p = threadIdx.x; p < HW; p += blockDim.x) {
        const int hy = p / W;
        const int wx = p - hy * W;
        float acc = bv;
        for (int ci = 0; ci < Cin; ++ci) {
            const Tin* inc = in + ((size_t)m * Cin + ci) * HW;
            const float* wc = wco + ci * 9;
#pragma unroll
            for (int ky = 0; ky < 3; ++ky) {
                const int iy = hy + ky - 1;
                if (iy < 0 || iy >= H) continue;
#pragma unroll
                for (int kx = 0; kx < 3; ++kx) {
                    const int ix = wx + kx - 1;
                    if (ix < 0 || ix >= W) continue;
                    acc += (float)inc[iy * W + ix] * wc[ky * 3 + kx];
                }
            }
        }
        y[((size_t)m * Cout + co) * HW + p] = acc;
        lsum += acc;
        lsq += acc * acc;
    }

    __shared__ float r1[256];
    __shared__ float r2[256];
    const int tid = threadIdx.x;
    r1[tid] = lsum;
    r2[tid] = lsq;
    __syncthreads();
    for (int s = blockDim.x >> 1; s > 0; s >>= 1) {
        if (tid < s) {
            r1[tid] += r1[tid + s];
            r2[tid] += r2[tid + s];
        }
        __syncthreads();
    }
    if (tid == 0) {
        atomicAdd(&ssum[co], r1[0]);
        atomicAdd(&ssq[co], r2[0]);
    }
}

// ---------------------------------------------------------------------------
// Tiled spike conv: grid (1024/IMPB, COUT/8), block 256 = IMPB * HW/4.
// Each thread: 1x4 pixel strip x 8 output channels, fp32 accumulators.
// LDS: spike halo tile [IMPB][8ci][(H+2)(W+2)] u8 + weights [8ci][9][8co] f32.
// ---------------------------------------------------------------------------
template <int CIN, int COUT, int H, int W, int IMPB>
__global__ __launch_bounds__(256) void conv_tiled_kernel(
    const uint8_t* __restrict__ in, const float* __restrict__ wgt,
    const float* __restrict__ bias, float* __restrict__ y,
    float* __restrict__ ssum, float* __restrict__ ssq)
{
    constexpr int HW = H * W;
    constexpr int HP = H + 2, WP = W + 2;
    constexpr int CICH = 8;   // input-channel chunk
    constexpr int COCH = 8;   // output-channel chunk
    constexpr int SPB = IMPB * CICH * HP * WP;

    __shared__ uint8_t sp[SPB];
    __shared__ float wl[CICH * 9 * COCH];
    __shared__ float bn_acc[2 * COCH];

    const int tid = threadIdx.x;
    for (int i = tid; i < SPB; i += 256) sp[i] = 0;   // halo stays 0 forever
    if (tid < 2 * COCH) bn_acc[tid] = 0.0f;

    constexpr int SPI = HW / 4;          // strips per image
    const int strip = tid % SPI;
    const int img   = tid / SPI;
    const int y0 = strip / (W / 4);
    const int x0 = (strip % (W / 4)) * 4;
    const int m   = blockIdx.x * IMPB + img;
    const int co0 = blockIdx.y * COCH;

    float acc[4][COCH];
#pragma unroll
    for (int p = 0; p < 4; ++p)
#pragma unroll
        for (int c = 0; c < COCH; ++c) acc[p][c] = 0.0f;

    constexpr int NCC = CIN / CICH;
    for (int cc = 0; cc < NCC; ++cc) {
        __syncthreads();
        const int ci0 = cc * CICH;
        // ---- stage spikes: IMPB*CICH*HW = 8192 bytes, u32 reads ----
#pragma unroll
        for (int it = 0; it < (IMPB * CICH * HW) / (256 * 4); ++it) {
            const int idx4 = (it * 256 + tid) * 4;
            const int px  = idx4 % HW;
            const int rem = idx4 / HW;           // img*CICH + ci_local
            const int cil = rem % CICH;
            const int im  = rem / CICH;
            const uint32_t v = *(const uint32_t*)(
                in + ((size_t)(blockIdx.x * IMPB + im) * CIN + ci0 + cil) * HW + px);
            const int yy = px / W, xx = px % W;  // xx multiple of 4, same row
            uint8_t* d = sp + (((im * CICH + cil) * HP) + yy + 1) * WP + xx + 1;
            d[0] = (uint8_t)(v & 0xff);
            d[1] = (uint8_t)((v >> 8) & 0xff);
            d[2] = (uint8_t)((v >> 16) & 0xff);
            d[3] = (uint8_t)((v >> 24) & 0xff);
        }
        // ---- stage weights -> [ci][k][co] ----
        for (int i = tid; i < CICH * 9 * COCH; i += 256) {
            const int c = i % COCH;
            const int r = i / COCH;
            const int k = r % 9;
            const int cil = r / 9;
            wl[i] = wgt[((size_t)(co0 + c) * CIN + ci0 + cil) * 9 + k];
        }
        __syncthreads();
        // ---- compute ----
#pragma unroll
        for (int ci = 0; ci < CICH; ++ci) {
            const uint8_t* sb = sp + (((img * CICH + ci) * HP) + y0) * WP + x0;
            float s[3][6];
#pragma unroll
            for (int r = 0; r < 3; ++r)
#pragma unroll
                for (int c = 0; c < 6; ++c)
                    s[r][c] = (float)sb[r * WP + c];
            const float* wp_ = wl + ci * 9 * COCH;
#pragma unroll
            for (int ky = 0; ky < 3; ++ky)
#pragma unroll
                for (int kx = 0; kx < 3; ++kx) {
                    const float4 wa = *(const float4*)(wp_ + (ky * 3 + kx) * COCH);
                    const float4 wb = *(const float4*)(wp_ + (ky * 3 + kx) * COCH + 4);
#pragma unroll
                    for (int p = 0; p < 4; ++p) {
                        const float sv = s[ky][kx + p];
                        acc[p][0] += sv * wa.x; acc[p][1] += sv * wa.y;
                        acc[p][2] += sv * wa.z; acc[p][3] += sv * wa.w;
                        acc[p][4] += sv * wb.x; acc[p][5] += sv * wb.y;
                        acc[p][6] += sv * wb.z; acc[p][7] += sv * wb.w;
                    }
                }
        }
    }
    // ---- epilogue: bias, y write, BN stats ----
#pragma unroll
    for (int c = 0; c < COCH; ++c) {
        const float bv = bias[co0 + c];
        const float v0 = acc[0][c] + bv, v1 = acc[1][c] + bv;
        const float v2 = acc[2][c] + bv, v3 = acc[3][c] + bv;
        float bsum = v0 + v1 + v2 + v3;
        float bsq  = v0 * v0 + v1 * v1 + v2 * v2 + v3 * v3;
        float4 o; o.x = v0; o.y = v1; o.z = v2; o.w = v3;
        *(float4*)(y + ((size_t)m * COUT + co0 + c) * HW + y0 * W + x0) = o;
#pragma unroll
        for (int off = 32; off > 0; off >>= 1) {
            bsum += __shfl_down(bsum, off, 64);
            bsq  += __shfl_down(bsq, off, 64);
        }
        if ((tid & 63) == 0) {
            atomicAdd(&bn_acc[c], bsum);
            atomicAdd(&bn_acc[COCH + c], bsq);
        }
    }
    __syncthreads();
    if (tid < COCH) atomicAdd(&ssum[co0 + tid], bn_acc[tid]);
    else if (tid < 2 * COCH) atomicAdd(&ssq[co0 + tid - COCH], bn_acc[tid]);
}

// Layer-1 BN+LIF: y is [N,C,HW] (same for every t). Emits spikes for all T.
__global__ void bnlif1_kernel(const float* __restrict__ y,
                              const float* __restrict__ ssum,
                              const float* __restrict__ ssq,
                              const float* __restrict__ g,
                              const float* __restrict__ be,
                              uint8_t* __restrict__ s,
                              int C, int HW, float invM) {
    const size_t total = (size_t)NBATCH * C * HW;
    const size_t i = (size_t)blockIdx.x * blockDim.x + threadIdx.x;
    if (i >= total) return;
    const int c = (int)((i / HW) % C);
    const float m = ssum[c] * invM;
    const float var = ssq[c] * invM - m * m;
    const float inv = g[c] / sqrtf(var + 1e-5f);
    const float z = y[i] * inv + (be[c] - m * inv);
    float v = 0.0f;
#pragma unroll
    for (int t = 0; t < T_STEPS; ++t) {
        v += (z - v) * 0.5f;
        const float sp = (v >= 1.0f) ? 1.0f : 0.0f;
        s[(size_t)t * total + i] = (uint8_t)sp;
        v *= (1.0f - sp);
    }
}

// BN+LIF (no pool): y [T*N, C, HW] -> spikes same layout.
__global__ void bnlif_kernel(const float* __restrict__ y,
                             const float* __restrict__ ssum,
                             const float* __restrict__ ssq,
                             const float* __restrict__ g,
                             const float* __restrict__ be,
                             uint8_t* __restrict__ s,
                             int C, int HW, float invM) {
    const size_t total = (size_t)NBATCH * C * HW;  // per-timestep elements
    const size_t i = (size_t)blockIdx.x * blockDim.x + threadIdx.x;
    if (i >= total) return;
    const int c = (int)((i / HW) % C);
    const float m = ssum[c] * invM;
    const float var = ssq[c] * invM - m * m;
    const float inv = g[c] / sqrtf(var + 1e-5f);
    const float sh = be[c] - m * inv;
    float v = 0.0f;
#pragma unroll
    for (int t = 0; t < T_STEPS; ++t) {
        const float z = y[(size_t)t * total + i] * inv + sh;
        v += (z - v) * 0.5f;
        const float sp = (v >= 1.0f) ? 1.0f : 0.0f;
        s[(size_t)t * total + i] = (uint8_t)sp;
        v *= (1.0f - sp);
    }
}

// BN+LIF fused with 2x2 max-pool (OR of binary spikes).
__global__ void bnlifpool_kernel(const float* __restrict__ y,
                                 const float* __restrict__ ssum,
                                 const float* __restrict__ ssq,
                                 const float* __restrict__ g,
                                 const float* __restrict__ be,
                                 uint8_t* __restrict__ p,
                                 int C, int H, int W, float invM) {
    const int PH = H >> 1, PW = W >> 1;
    const size_t ptotal = (size_t)NBATCH * C * PH * PW;
    const size_t i = (size_t)blockIdx.x * blockDim.x + threadIdx.x;
    if (i >= ptotal) return;
    const int pw = (int)(i % PW);
    const int ph = (int)((i / PW) % PH);
    const int c = (int)((i / ((size_t)PW * PH)) % C);
    const int n = (int)(i / ((size_t)PW * PH * C));

    const float m = ssum[c] * invM;
    const float var = ssq[c] * invM - m * m;
    const float inv = g[c] / sqrtf(var + 1e-5f);
    const float sh = be[c] - m * inv;

    const size_t ystride = (size_t)NBATCH * C * H * W;
    const size_t base = (((size_t)n * C + c) * H + 2 * ph) * W + 2 * pw;

    float v00 = 0.f, v01 = 0.f, v10 = 0.f, v11 = 0.f;
#pragma unroll
    for (int t = 0; t < T_STEPS; ++t) {
        const float* yt = y + (size_t)t * ystride + base;
        const float z00 = yt[0] * inv + sh;
        const float z01 = yt[1] * inv + sh;
        const float z10 = yt[W] * inv + sh;
        const float z11 = yt[W + 1] * inv + sh;
        v00 += (z00 - v00) * 0.5f;
        v01 += (z01 - v01) * 0.5f;
        v10 += (z10 - v10) * 0.5f;
        v11 += (z11 - v11) * 0.5f;
        const float s00 = (v00 >= 1.0f) ? 1.0f : 0.0f;
        const float s01 = (v01 >= 1.0f) ? 1.0f : 0.0f;
        const float s10 = (v10 >= 1.0f) ? 1.0f : 0.0f;
        const float s11 = (v11 >= 1.0f) ? 1.0f : 0.0f;
        v00 *= (1.0f - s00);
        v01 *= (1.0f - s01);
        v10 *= (1.0f - s10);
        v11 *= (1.0f - s11);
        const float mx = fmaxf(fmaxf(s00, s01), fmaxf(s10, s11));
        p[(size_t)t * ptotal + i] = (uint8_t)mx;
    }
}

// fc1: f [T*N, 2048] uint8, w [128,2048] -> h [T*N,128]
__global__ void fc1_kernel(const uint8_t* __restrict__ f,
                           const float* __restrict__ w,
                           const float* __restrict__ b,
                           float* __restrict__ h) {
    __shared__ float fs[2048];
    const int r = blockIdx.x;
    const uint8_t* fr = f + (size_t)r * 2048;
    for (int i = threadIdx.x; i < 2048; i += blockDim.x)
        fs[i] = (float)fr[i];
    __syncthreads();
    const int o = threadIdx.x;  // blockDim = 128
    const float4* fv = (const float4*)fs;
    const float4* wv = (const float4*)(w + (size_t)o * 2048);
    float acc = b[o];
    for (int i = 0; i < 512; ++i) {
        const float4 a = fv[i];
        const float4 ww = wv[i];
        acc += a.x * ww.x + a.y * ww.y + a.z * ww.z + a.w * ww.w;
    }
    h[(size_t)r * 128 + o] = acc;
}

// LIF over T for fc1 outputs: h [T, NF] -> spikes uint8 same layout.
__global__ void lif_fc_kernel(const float* __restrict__ h,
                              uint8_t* __restrict__ s, int NF) {
    const int i = blockIdx.x * blockDim.x + threadIdx.x;
    if (i >= NF) return;
    float v = 0.0f;
#pragma unroll
    for (int t = 0; t < T_STEPS; ++t) {
        const float z = h[(size_t)t * NF + i];
        v += (z - v) * 0.5f;
        const float sp = (v >= 1.0f) ? 1.0f : 0.0f;
        s[(size_t)t * NF + i] = (uint8_t)sp;
        v *= (1.0f - sp);
    }
}

// fc2 + LIF + mean over T. sh [T,N,128] uint8, w [10,128]. out [N,10].
__global__ void fc2_kernel(const uint8_t* __restrict__ sh,
                           const float* __restrict__ w,
                           const float* __restrict__ b,
                           float* __restrict__ out) {
    const int i = blockIdx.x * blockDim.x + threadIdx.x;
    if (i >= NBATCH * 10) return;
    const int k = i % 10;
    const int n = i / 10;
    float v = 0.0f, acc = 0.0f;
    for (int t = 0; t < T_STEPS; ++t) {
        const uint8_t* row = sh + ((size_t)t * NBATCH + n) * 128;
        float z = b[k];
        for (int o = 0; o < 128; ++o)
            z += (float)row[o] * w[k * 128 + o];
        v += (z - v) * 0.5f;
        const float sp = (v >= 1.0f) ? 1.0f : 0.0f;
        acc += sp;
        v *= (1.0f - sp);
    }
    out[i] = acc * (1.0f / T_STEPS);
}

extern "C" void kernel_launch(void* const* d_in, const int* in_sizes, int n_in,
                              void* d_out, int out_size, void* d_ws, size_t ws_size,
                              hipStream_t stream) {
    const float* x   = (const float*)d_in[0];
    const float* W1  = (const float*)d_in[1];
    const float* Bi1 = (const float*)d_in[2];
    const float* G1  = (const float*)d_in[3];
    const float* BE1 = (const float*)d_in[4];
    const float* W2  = (const float*)d_in[5];
    const float* Bi2 = (const float*)d_in[6];
    const float* G2  = (const float*)d_in[7];
    const float* BE2 = (const float*)d_in[8];
    const float* W3  = (const float*)d_in[9];
    const float* Bi3 = (const float*)d_in[10];
    const float* G3  = (const float*)d_in[11];
    const float* BE3 = (const float*)d_in[12];
    const float* W4  = (const float*)d_in[13];
    const float* Bi4 = (const float*)d_in[14];
    const float* G4  = (const float*)d_in[15];
    const float* BE4 = (const float*)d_in[16];
    const float* W5  = (const float*)d_in[17];
    const float* Bi5 = (const float*)d_in[18];
    const float* G5  = (const float*)d_in[19];
    const float* BE5 = (const float*)d_in[20];
    const float* W6  = (const float*)d_in[21];
    const float* Bi6 = (const float*)d_in[22];
    const float* G6  = (const float*)d_in[23];
    const float* BE6 = (const float*)d_in[24];
    const float* FC1W = (const float*)d_in[25];
    const float* FC1B = (const float*)d_in[26];
    const float* FC2W = (const float*)d_in[27];
    const float* FC2B = (const float*)d_in[28];

    // workspace layout
    uint8_t* ws = (uint8_t*)d_ws;
    float*   Y     = (float*)ws;                       // 134,217,728 B (max y: layer2)
    uint8_t* A     = ws + 134217728;                   // 33,554,432 B spike ping
    uint8_t* Bb    = A + 33554432;                     //  8,388,608 B spike pong
    float*   stats = (float*)(Bb + 8388608);           //  6,144 B (6 layers x 256 floats)
    float*   h     = (float*)((uint8_t*)stats + 8192); //  524,288 B fc1 out
    uint8_t* sh    = (uint8_t*)h + 524288;             //  131,072 B fc1 spikes

    zero_kernel<<<(1536 + 255) / 256, 256, 0, stream>>>(stats, 1536);

    const int TN = T_STEPS * NBATCH;  // 1024

    // ---- layer 1: conv(3->32) over N only (T-invariant), BN, LIF ----
    {
        dim3 g(NBATCH, 32);
        conv3x3_kernel<float><<<g, 256, 0, stream>>>(x, W1, Bi1, Y,
                                                     stats + 0, stats + 128, 3, 32, 32);
        const int total = NBATCH * 32 * 1024;
        bnlif1_kernel<<<total / 256, 256, 0, stream>>>(Y, stats + 0, stats + 128,
                                                       G1, BE1, A, 32, 1024,
                                                       1.0f / 131072.0f);
    }
    // ---- layer 2: conv(32->32) 32x32, BN, LIF, pool -> Bb [T,N,32,16,16] ----
    {
        dim3 g(TN, 32 / 8);
        conv_tiled_kernel<32, 32, 32, 32, 1><<<g, 256, 0, stream>>>(
            A, W2, Bi2, Y, stats + 256, stats + 384);
        const int ptotal = NBATCH * 32 * 256;
        bnlifpool_kernel<<<ptotal / 256, 256, 0, stream>>>(Y, stats + 256, stats + 384,
                                                           G2, BE2, Bb, 32, 32, 32,
                                                           1.0f / (1024.0f * 1024.0f));
    }
    // ---- layer 3: conv(32->64) 16x16, BN, LIF -> A ----
    {
        dim3 g(TN / 4, 64 / 8);
        conv_tiled_kernel<32, 64, 16, 16, 4><<<g, 256, 0, stream>>>(
            Bb, W3, Bi3, Y, stats + 512, stats + 640);
        const int total = NBATCH * 64 * 256;
        bnlif_kernel<<<total / 256, 256, 0, stream>>>(Y, stats + 512, stats + 640,
                                                      G3, BE3, A, 64, 256,
                                                      1.0f / (1024.0f * 256.0f));
    }
    // ---- layer 4: conv(64->64) 16x16, BN, LIF, pool -> Bb [T,N,64,8,8] ----
    {
        dim3 g(TN / 4, 64 / 8);
        conv_tiled_kernel<64, 64, 16, 16, 4><<<g, 256, 0, stream>>>(
            A, W4, Bi4, Y, stats + 768, stats + 896);
        const int ptotal = NBATCH * 64 * 64;
        bnlifpool_kernel<<<ptotal / 256, 256, 0, stream>>>(Y, stats + 768, stats + 896,
                                                           G4, BE4, Bb, 64, 16, 16,
                                                           1.0f / (1024.0f * 256.0f));
    }
    // ---- layer 5: conv(64->128) 8x8, BN, LIF -> A ----
    {
        dim3 g(TN / 16, 128 / 8);
        conv_tiled_kernel<64, 128, 8, 8, 16><<<g, 256, 0, stream>>>(
            Bb, W5, Bi5, Y, stats + 1024, stats + 1152);
        const int total = NBATCH * 128 * 64;
        bnlif_kernel<<<total / 256, 256, 0, stream>>>(Y, stats + 1024, stats + 1152,
                                                      G5, BE5, A, 128, 64,
                                                      1.0f / (1024.0f * 64.0f));
    }
    // ---- layer 6: conv(128->128) 8x8, BN, LIF, pool -> Bb [T,N,128,4,4] ----
    {
        dim3 g(TN / 16, 128 / 8);
        conv_tiled_kernel<128, 128, 8, 8, 16><<<g, 256, 0, stream>>>(
            A, W6, Bi6, Y, stats + 1280, stats + 1408);
        const int ptotal = NBATCH * 128 * 16;
        bnlifpool_kernel<<<ptotal / 256, 256, 0, stream>>>(Y, stats + 1280, stats + 1408,
                                                           G6, BE6, Bb, 128, 8, 8,
                                                           1.0f / (1024.0f * 64.0f));
    }
    // ---- fc1 (2048->128) + LIF ----
    fc1_kernel<<<TN, 128, 0, stream>>>(Bb, FC1W, FC1B, h);
    lif_fc_kernel<<<(NBATCH * 128 + 255) / 256, 256, 0, stream>>>(h, sh, NBATCH * 128);
    // ---- fc2 (128->10) + LIF + mean ----
    fc2_kernel<<<(NBATCH * 10 + 255) / 256, 256, 0, stream>>>(sh, FC2W, FC2B, (float*)d_out);
}

// Round 3
// 1340.561 us; speedup vs baseline: 7.6604x; 1.4489x over previous
//
#include <hip/hip_runtime.h>
#include <stdint.h>

// ---------------------------------------------------------------------------
// EnhancedSNNCifar: T=8 SNN forward.
//   conv1(3->32,32x32) BN LIF            [T-invariant conv: computed for N only]
//   conv2(32->32,32x32) BN LIF pool->16
//   conv3(32->64,16x16) BN LIF
//   conv4(64->64,16x16) BN LIF pool->8
//   conv5(64->128,8x8) BN LIF
//   conv6(128->128,8x8) BN LIF pool->4
//   fc1(2048->128) LIF ; fc2(128->10) LIF ; mean over T
// Spikes stored as uint8 {0,1}. BN is training-mode over merged T*N batch.
//
// R3: tiled conv gets (a) cross-barrier prefetch (globals for chunk k+1 issue
//     before the FMA stretch of chunk k, so the barrier's vmcnt(0) drain is
//     latency-free), (b) fp32 spike tiles in LDS (convert once at staging; hot
//     loop is pure ds_read_b32 + v_fma), (c) CICH=4 on layers 3-6 for >=5
//     blocks/CU. fp32 everywhere -> bitwise-stable vs R2 (absmax 0.0).
// ---------------------------------------------------------------------------

#define T_STEPS 8
#define NBATCH 128

__global__ void zero_kernel(float* p, int n) {
    int i = blockIdx.x * blockDim.x + threadIdx.x;
    if (i < n) p[i] = 0.0f;
}

// Direct 3x3 pad-1 conv (used only for conv1: Cin=3, fp32 input, M=128).
template <typename Tin>
__global__ void conv3x3_kernel(const Tin* __restrict__ in,
                               const float* __restrict__ wgt,
                               const float* __restrict__ bias,
                               float* __restrict__ y,
                               float* __restrict__ ssum,
                               float* __restrict__ ssq,
                               int Cin, int H, int W) {
    const int m  = blockIdx.x;
    const int co = blockIdx.y;
    const int Cout = gridDim.y;
    const int HW = H * W;

    const float* wco = wgt + (size_t)co * Cin * 9;
    const float bv = bias[co];

    float lsum = 0.0f, lsq = 0.0f;

    for (int p = threadIdx.x; p < HW; p += blockDim.x) {
        const int hy = p / W;
        const int wx = p - hy * W;
        float acc = bv;
        for (int ci = 0; ci < Cin; ++ci) {
            const Tin* inc = in + ((size_t)m * Cin + ci) * HW;
            const float* wc = wco + ci * 9;
#pragma unroll
            for (int ky = 0; ky < 3; ++ky) {
                const int iy = hy + ky - 1;
                if (iy < 0 || iy >= H) continue;
#pragma unroll
                for (int kx = 0; kx < 3; ++kx) {
                    const int ix = wx + kx - 1;
                    if (ix < 0 || ix >= W) continue;
                    acc += (float)inc[iy * W + ix] * wc[ky * 3 + kx];
                }
            }
        }
        y[((size_t)m * Cout + co) * HW + p] = acc;
        lsum += acc;
        lsq += acc * acc;
    }

    __shared__ float r1[256];
    __shared__ float r2[256];
    const int tid = threadIdx.x;
    r1[tid] = lsum;
    r2[tid] = lsq;
    __syncthreads();
    for (int s = blockDim.x >> 1; s > 0; s >>= 1) {
        if (tid < s) {
            r1[tid] += r1[tid + s];
            r2[tid] += r2[tid + s];
        }
        __syncthreads();
    }
    if (tid == 0) {
        atomicAdd(&ssum[co], r1[0]);
        atomicAdd(&ssq[co], r2[0]);
    }
}

// ---------------------------------------------------------------------------
// Tiled spike conv: grid (1024/IMPB, COUT/8), block 256 = IMPB * HW/4.
// Each thread: 1x4 pixel strip x 8 output channels, fp32 accumulators.
// LDS: fp32 spike halo tile [IMPB][CICH][(H+2)(W+2)] + weights [ci][k][co].
// Prefetch: globals for chunk k+1 are issued after the second barrier of
// chunk k, so their latency hides under the FMA stretch.
// ---------------------------------------------------------------------------
template <int CIN, int COUT, int H, int W, int IMPB, int CICH>
__global__ __launch_bounds__(256) void conv_tiled_kernel(
    const uint8_t* __restrict__ in, const float* __restrict__ wgt,
    const float* __restrict__ bias, float* __restrict__ y,
    float* __restrict__ ssum, float* __restrict__ ssq)
{
    constexpr int HW = H * W;
    constexpr int HP = H + 2, WP = W + 2;
    constexpr int COCH = 8;
    constexpr int SPW = IMPB * CICH * HP * WP;      // floats in spike tile
    constexpr int WTOT = CICH * 9 * COCH;
    constexpr int NLD = (IMPB * CICH * HW / 4) / 256;   // u32 loads/thread/chunk
    constexpr int NWL = (WTOT + 255) / 256;
    constexpr int NCC = CIN / CICH;
    static_assert(IMPB * (HW / 4) == 256, "block mapping");
    static_assert((IMPB * CICH * HW / 4) % 256 == 0, "stage mapping");

    __shared__ float sp[SPW];
    __shared__ float wl[WTOT];
    __shared__ float bn_acc[2 * COCH];

    const int tid = threadIdx.x;
    for (int i = tid; i < SPW; i += 256) sp[i] = 0.0f;  // halo stays 0 forever
    if (tid < 2 * COCH) bn_acc[tid] = 0.0f;

    constexpr int SPI = HW / 4;          // strips per image
    const int strip = tid % SPI;
    const int img   = tid / SPI;
    const int y0 = strip / (W / 4);
    const int x0 = (strip % (W / 4)) * 4;
    const int m   = blockIdx.x * IMPB + img;
    const int co0 = blockIdx.y * COCH;

    float acc[4][COCH];
#pragma unroll
    for (int p = 0; p < 4; ++p)
#pragma unroll
        for (int c = 0; c < COCH; ++c) acc[p][c] = 0.0f;

    uint32_t ps[NLD];
    float pw[NWL];

    auto load_globals = [&](int cc) {
#pragma unroll
        for (int it = 0; it < NLD; ++it) {
            const int idx4 = (it * 256 + tid) * 4;
            const int px  = idx4 % HW;
            const int rem = idx4 / HW;           // im*CICH + cil
            const int cil = rem % CICH;
            const int im  = rem / CICH;
            ps[it] = *(const uint32_t*)(
                in + ((size_t)(blockIdx.x * IMPB + im) * CIN + cc * CICH + cil) * HW + px);
        }
#pragma unroll
        for (int iw = 0; iw < NWL; ++iw) {
            const int i = iw * 256 + tid;
            if (i < WTOT) {
                const int c   = i % COCH;
                const int k   = (i / COCH) % 9;
                const int cil = i / (9 * COCH);
                pw[iw] = wgt[((size_t)(co0 + c) * CIN + cc * CICH + cil) * 9 + k];
            }
        }
    };
    auto store_lds = [&]() {
#pragma unroll
        for (int it = 0; it < NLD; ++it) {
            const int idx4 = (it * 256 + tid) * 4;
            const int px  = idx4 % HW;
            const int rem = idx4 / HW;
            const int cil = rem % CICH;
            const int im  = rem / CICH;
            const int yy = px / W, xx = px - (px / W) * W;  // xx multiple of 4
            float* d = sp + ((im * CICH + cil) * HP + yy + 1) * WP + xx + 1;
            const uint32_t v = ps[it];
            d[0] = (float)(v & 0xff);
            d[1] = (float)((v >> 8) & 0xff);
            d[2] = (float)((v >> 16) & 0xff);
            d[3] = (float)((v >> 24) & 0xff);
        }
#pragma unroll
        for (int iw = 0; iw < NWL; ++iw) {
            const int i = iw * 256 + tid;
            if (i < WTOT) wl[i] = pw[iw];
        }
    };

    load_globals(0);
#pragma clang loop unroll(disable)
    for (int cc = 0; cc < NCC; ++cc) {
        __syncthreads();          // LDS free (previous compute done)
        store_lds();
        __syncthreads();          // tile visible
        if (cc + 1 < NCC) load_globals(cc + 1);   // in flight during compute
        // ---- compute ----
#pragma unroll
        for (int ci = 0; ci < CICH; ++ci) {
            const float* sb = sp + ((img * CICH + ci) * HP + y0) * WP + x0;
            float s[3][6];
#pragma unroll
            for (int r = 0; r < 3; ++r)
#pragma unroll
                for (int c = 0; c < 6; ++c)
                    s[r][c] = sb[r * WP + c];
            const float* wp_ = wl + ci * 9 * COCH;
#pragma unroll
            for (int ky = 0; ky < 3; ++ky)
#pragma unroll
                for (int kx = 0; kx < 3; ++kx) {
                    const float4 wa = *(const float4*)(wp_ + (ky * 3 + kx) * COCH);
                    const float4 wb = *(const float4*)(wp_ + (ky * 3 + kx) * COCH + 4);
#pragma unroll
                    for (int p = 0; p < 4; ++p) {
                        const float sv = s[ky][kx + p];
                        acc[p][0] += sv * wa.x; acc[p][1] += sv * wa.y;
                        acc[p][2] += sv * wa.z; acc[p][3] += sv * wa.w;
                        acc[p][4] += sv * wb.x; acc[p][5] += sv * wb.y;
                        acc[p][6] += sv * wb.z; acc[p][7] += sv * wb.w;
                    }
                }
        }
    }
    // ---- epilogue: bias, y write, BN stats ----
#pragma unroll
    for (int c = 0; c < COCH; ++c) {
        const float bv = bias[co0 + c];
        const float v0 = acc[0][c] + bv, v1 = acc[1][c] + bv;
        const float v2 = acc[2][c] + bv, v3 = acc[3][c] + bv;
        float bsum = v0 + v1 + v2 + v3;
        float bsq  = v0 * v0 + v1 * v1 + v2 * v2 + v3 * v3;
        float4 o; o.x = v0; o.y = v1; o.z = v2; o.w = v3;
        *(float4*)(y + ((size_t)m * COUT + co0 + c) * HW + y0 * W + x0) = o;
#pragma unroll
        for (int off = 32; off > 0; off >>= 1) {
            bsum += __shfl_down(bsum, off, 64);
            bsq  += __shfl_down(bsq, off, 64);
        }
        if ((tid & 63) == 0) {
            atomicAdd(&bn_acc[c], bsum);
            atomicAdd(&bn_acc[COCH + c], bsq);
        }
    }
    __syncthreads();
    if (tid < COCH) atomicAdd(&ssum[co0 + tid], bn_acc[tid]);
    else if (tid < 2 * COCH) atomicAdd(&ssq[co0 + tid - COCH], bn_acc[tid]);
}

// Layer-1 BN+LIF: y is [N,C,HW] (same for every t). Emits spikes for all T.
__global__ void bnlif1_kernel(const float* __restrict__ y,
                              const float* __restrict__ ssum,
                              const float* __restrict__ ssq,
                              const float* __restrict__ g,
                              const float* __restrict__ be,
                              uint8_t* __restrict__ s,
                              int C, int HW, float invM) {
    const size_t total = (size_t)NBATCH * C * HW;
    const size_t i = (size_t)blockIdx.x * blockDim.x + threadIdx.x;
    if (i >= total) return;
    const int c = (int)((i / HW) % C);
    const float m = ssum[c] * invM;
    const float var = ssq[c] * invM - m * m;
    const float inv = g[c] / sqrtf(var + 1e-5f);
    const float z = y[i] * inv + (be[c] - m * inv);
    float v = 0.0f;
#pragma unroll
    for (int t = 0; t < T_STEPS; ++t) {
        v += (z - v) * 0.5f;
        const float sp = (v >= 1.0f) ? 1.0f : 0.0f;
        s[(size_t)t * total + i] = (uint8_t)sp;
        v *= (1.0f - sp);
    }
}

// BN+LIF (no pool): y [T*N, C, HW] -> spikes same layout.
__global__ void bnlif_kernel(const float* __restrict__ y,
                             const float* __restrict__ ssum,
                             const float* __restrict__ ssq,
                             const float* __restrict__ g,
                             const float* __restrict__ be,
                             uint8_t* __restrict__ s,
                             int C, int HW, float invM) {
    const size_t total = (size_t)NBATCH * C * HW;
    const size_t i = (size_t)blockIdx.x * blockDim.x + threadIdx.x;
    if (i >= total) return;
    const int c = (int)((i / HW) % C);
    const float m = ssum[c] * invM;
    const float var = ssq[c] * invM - m * m;
    const float inv = g[c] / sqrtf(var + 1e-5f);
    const float sh = be[c] - m * inv;
    float v = 0.0f;
#pragma unroll
    for (int t = 0; t < T_STEPS; ++t) {
        const float z = y[(size_t)t * total + i] * inv + sh;
        v += (z - v) * 0.5f;
        const float sp = (v >= 1.0f) ? 1.0f : 0.0f;
        s[(size_t)t * total + i] = (uint8_t)sp;
        v *= (1.0f - sp);
    }
}

// BN+LIF fused with 2x2 max-pool (OR of binary spikes).
__global__ void bnlifpool_kernel(const float* __restrict__ y,
                                 const float* __restrict__ ssum,
                                 const float* __restrict__ ssq,
                                 const float* __restrict__ g,
                                 const float* __restrict__ be,
                                 uint8_t* __restrict__ p,
                                 int C, int H, int W, float invM) {
    const int PH = H >> 1, PW = W >> 1;
    const size_t ptotal = (size_t)NBATCH * C * PH * PW;
    const size_t i = (size_t)blockIdx.x * blockDim.x + threadIdx.x;
    if (i >= ptotal) return;
    const int pw = (int)(i % PW);
    const int ph = (int)((i / PW) % PH);
    const int c = (int)((i / ((size_t)PW * PH)) % C);
    const int n = (int)(i / ((size_t)PW * PH * C));

    const float m = ssum[c] * invM;
    const float var = ssq[c] * invM - m * m;
    const float inv = g[c] / sqrtf(var + 1e-5f);
    const float sh = be[c] - m * inv;

    const size_t ystride = (size_t)NBATCH * C * H * W;
    const size_t base = (((size_t)n * C + c) * H + 2 * ph) * W + 2 * pw;

    float v00 = 0.f, v01 = 0.f, v10 = 0.f, v11 = 0.f;
#pragma unroll
    for (int t = 0; t < T_STEPS; ++t) {
        const float* yt = y + (size_t)t * ystride + base;
        const float z00 = yt[0] * inv + sh;
        const float z01 = yt[1] * inv + sh;
        const float z10 = yt[W] * inv + sh;
        const float z11 = yt[W + 1] * inv + sh;
        v00 += (z00 - v00) * 0.5f;
        v01 += (z01 - v01) * 0.5f;
        v10 += (z10 - v10) * 0.5f;
        v11 += (z11 - v11) * 0.5f;
        const float s00 = (v00 >= 1.0f) ? 1.0f : 0.0f;
        const float s01 = (v01 >= 1.0f) ? 1.0f : 0.0f;
        const float s10 = (v10 >= 1.0f) ? 1.0f : 0.0f;
        const float s11 = (v11 >= 1.0f) ? 1.0f : 0.0f;
        v00 *= (1.0f - s00);
        v01 *= (1.0f - s01);
        v10 *= (1.0f - s10);
        v11 *= (1.0f - s11);
        const float mx = fmaxf(fmaxf(s00, s01), fmaxf(s10, s11));
        p[(size_t)t * ptotal + i] = (uint8_t)mx;
    }
}

// fc1: f [T*N, 2048] uint8, w [128,2048] -> h [T*N,128]
__global__ void fc1_kernel(const uint8_t* __restrict__ f,
                           const float* __restrict__ w,
                           const float* __restrict__ b,
                           float* __restrict__ h) {
    __shared__ float fs[2048];
    const int r = blockIdx.x;
    const uint8_t* fr = f + (size_t)r * 2048;
    for (int i = threadIdx.x; i < 2048; i += blockDim.x)
        fs[i] = (float)fr[i];
    __syncthreads();
    const int o = threadIdx.x;  // blockDim = 128
    const float4* fv = (const float4*)fs;
    const float4* wv = (const float4*)(w + (size_t)o * 2048);
    float acc = b[o];
    for (int i = 0; i < 512; ++i) {
        const float4 a = fv[i];
        const float4 ww = wv[i];
        acc += a.x * ww.x + a.y * ww.y + a.z * ww.z + a.w * ww.w;
    }
    h[(size_t)r * 128 + o] = acc;
}

// LIF over T for fc1 outputs: h [T, NF] -> spikes uint8 same layout.
__global__ void lif_fc_kernel(const float* __restrict__ h,
                              uint8_t* __restrict__ s, int NF) {
    const int i = blockIdx.x * blockDim.x + threadIdx.x;
    if (i >= NF) return;
    float v = 0.0f;
#pragma unroll
    for (int t = 0; t < T_STEPS; ++t) {
        const float z = h[(size_t)t * NF + i];
        v += (z - v) * 0.5f;
        const float sp = (v >= 1.0f) ? 1.0f : 0.0f;
        s[(size_t)t * NF + i] = (uint8_t)sp;
        v *= (1.0f - sp);
    }
}

// fc2 + LIF + mean over T. sh [T,N,128] uint8, w [10,128]. out [N,10].
__global__ void fc2_kernel(const uint8_t* __restrict__ sh,
                           const float* __restrict__ w,
                           const float* __restrict__ b,
                           float* __restrict__ out) {
    const int i = blockIdx.x * blockDim.x + threadIdx.x;
    if (i >= NBATCH * 10) return;
    const int k = i % 10;
    const int n = i / 10;
    float v = 0.0f, acc = 0.0f;
    for (int t = 0; t < T_STEPS; ++t) {
        const uint8_t* row = sh + ((size_t)t * NBATCH + n) * 128;
        float z = b[k];
        for (int o = 0; o < 128; ++o)
            z += (float)row[o] * w[k * 128 + o];
        v += (z - v) * 0.5f;
        const float sp = (v >= 1.0f) ? 1.0f : 0.0f;
        acc += sp;
        v *= (1.0f - sp);
    }
    out[i] = acc * (1.0f / T_STEPS);
}

extern "C" void kernel_launch(void* const* d_in, const int* in_sizes, int n_in,
                              void* d_out, int out_size, void* d_ws, size_t ws_size,
                              hipStream_t stream) {
    const float* x   = (const float*)d_in[0];
    const float* W1  = (const float*)d_in[1];
    const float* Bi1 = (const float*)d_in[2];
    const float* G1  = (const float*)d_in[3];
    const float* BE1 = (const float*)d_in[4];
    const float* W2  = (const float*)d_in[5];
    const float* Bi2 = (const float*)d_in[6];
    const float* G2  = (const float*)d_in[7];
    const float* BE2 = (const float*)d_in[8];
    const float* W3  = (const float*)d_in[9];
    const float* Bi3 = (const float*)d_in[10];
    const float* G3  = (const float*)d_in[11];
    const float* BE3 = (const float*)d_in[12];
    const float* W4  = (const float*)d_in[13];
    const float* Bi4 = (const float*)d_in[14];
    const float* G4  = (const float*)d_in[15];
    const float* BE4 = (const float*)d_in[16];
    const float* W5  = (const float*)d_in[17];
    const float* Bi5 = (const float*)d_in[18];
    const float* G5  = (const float*)d_in[19];
    const float* BE5 = (const float*)d_in[20];
    const float* W6  = (const float*)d_in[21];
    const float* Bi6 = (const float*)d_in[22];
    const float* G6  = (const float*)d_in[23];
    const float* BE6 = (const float*)d_in[24];
    const float* FC1W = (const float*)d_in[25];
    const float* FC1B = (const float*)d_in[26];
    const float* FC2W = (const float*)d_in[27];
    const float* FC2B = (const float*)d_in[28];

    // workspace layout
    uint8_t* ws = (uint8_t*)d_ws;
    float*   Y     = (float*)ws;                       // 134,217,728 B (max y: layer2)
    uint8_t* A     = ws + 134217728;                   // 33,554,432 B spike ping
    uint8_t* Bb    = A + 33554432;                     //  8,388,608 B spike pong
    float*   stats = (float*)(Bb + 8388608);           //  6,144 B (6 layers x 256 floats)
    float*   h     = (float*)((uint8_t*)stats + 8192); //  524,288 B fc1 out
    uint8_t* sh    = (uint8_t*)h + 524288;             //  131,072 B fc1 spikes

    zero_kernel<<<(1536 + 255) / 256, 256, 0, stream>>>(stats, 1536);

    const int TN = T_STEPS * NBATCH;  // 1024

    // ---- layer 1: conv(3->32) over N only (T-invariant), BN, LIF ----
    {
        dim3 g(NBATCH, 32);
        conv3x3_kernel<float><<<g, 256, 0, stream>>>(x, W1, Bi1, Y,
                                                     stats + 0, stats + 128, 3, 32, 32);
        const int total = NBATCH * 32 * 1024;
        bnlif1_kernel<<<total / 256, 256, 0, stream>>>(Y, stats + 0, stats + 128,
                                                       G1, BE1, A, 32, 1024,
                                                       1.0f / 131072.0f);
    }
    // ---- layer 2: conv(32->32) 32x32, BN, LIF, pool -> Bb [T,N,32,16,16] ----
    {
        dim3 g(TN, 32 / 8);
        conv_tiled_kernel<32, 32, 32, 32, 1, 8><<<g, 256, 0, stream>>>(
            A, W2, Bi2, Y, stats + 256, stats + 384);
        const int ptotal = NBATCH * 32 * 256;
        bnlifpool_kernel<<<ptotal / 256, 256, 0, stream>>>(Y, stats + 256, stats + 384,
                                                           G2, BE2, Bb, 32, 32, 32,
                                                           1.0f / (1024.0f * 1024.0f));
    }
    // ---- layer 3: conv(32->64) 16x16, BN, LIF -> A ----
    {
        dim3 g(TN / 4, 64 / 8);
        conv_tiled_kernel<32, 64, 16, 16, 4, 4><<<g, 256, 0, stream>>>(
            Bb, W3, Bi3, Y, stats + 512, stats + 640);
        const int total = NBATCH * 64 * 256;
        bnlif_kernel<<<total / 256, 256, 0, stream>>>(Y, stats + 512, stats + 640,
                                                      G3, BE3, A, 64, 256,
                                                      1.0f / (1024.0f * 256.0f));
    }
    // ---- layer 4: conv(64->64) 16x16, BN, LIF, pool -> Bb [T,N,64,8,8] ----
    {
        dim3 g(TN / 4, 64 / 8);
        conv_tiled_kernel<64, 64, 16, 16, 4, 4><<<g, 256, 0, stream>>>(
            A, W4, Bi4, Y, stats + 768, stats + 896);
        const int ptotal = NBATCH * 64 * 64;
        bnlifpool_kernel<<<ptotal / 256, 256, 0, stream>>>(Y, stats + 768, stats + 896,
                                                           G4, BE4, Bb, 64, 16, 16,
                                                           1.0f / (1024.0f * 256.0f));
    }
    // ---- layer 5: conv(64->128) 8x8, BN, LIF -> A ----
    {
        dim3 g(TN / 16, 128 / 8);
        conv_tiled_kernel<64, 128, 8, 8, 16, 4><<<g, 256, 0, stream>>>(
            Bb, W5, Bi5, Y, stats + 1024, stats + 1152);
        const int total = NBATCH * 128 * 64;
        bnlif_kernel<<<total / 256, 256, 0, stream>>>(Y, stats + 1024, stats + 1152,
                                                      G5, BE5, A, 128, 64,
                                                      1.0f / (1024.0f * 64.0f));
    }
    // ---- layer 6: conv(128->128) 8x8, BN, LIF, pool -> Bb [T,N,128,4,4] ----
    {
        dim3 g(TN / 16, 128 / 8);
        conv_tiled_kernel<128, 128, 8, 8, 16, 4><<<g, 256, 0, stream>>>(
            A, W6, Bi6, Y, stats + 1280, stats + 1408);
        const int ptotal = NBATCH * 128 * 16;
        bnlifpool_kernel<<<ptotal / 256, 256, 0, stream>>>(Y, stats + 1280, stats + 1408,
                                                           G6, BE6, Bb, 128, 8, 8,
                                                           1.0f / (1024.0f * 64.0f));
    }
    // ---- fc1 (2048->128) + LIF ----
    fc1_kernel<<<TN, 128, 0, stream>>>(Bb, FC1W, FC1B, h);
    lif_fc_kernel<<<(NBATCH * 128 + 255) / 256, 256, 0, stream>>>(h, sh, NBATCH * 128);
    // ---- fc2 (128->10) + LIF + mean ----
    fc2_kernel<<<(NBATCH * 10 + 255) / 256, 256, 0, stream>>>(sh, FC2W, FC2B, (float*)d_out);
}

// Round 4
// 1066.778 us; speedup vs baseline: 9.6264x; 1.2566x over previous
//
#include <hip/hip_runtime.h>
#include <stdint.h>

// ---------------------------------------------------------------------------
// EnhancedSNNCifar: T=8 SNN forward.
//   conv1(3->32,32x32) BN LIF            [T-invariant conv: computed for N only]
//   conv2(32->32,32x32) BN LIF pool->16
//   conv3(32->64,16x16) BN LIF
//   conv4(64->64,16x16) BN LIF pool->8
//   conv5(64->128,8x8) BN LIF
//   conv6(128->128,8x8) BN LIF pool->4
//   fc1(2048->128) LIF ; fc2(128->10) LIF ; mean over T
//
// R4: spike convs on MFMA (mfma_f32_16x16x32_bf16) as 9 shifted K=32 GEMMs.
//     Spikes u8 NHWC (exact in bf16); weights triple-bf16-split (h1+h2+h3,
//     residual < fp32 ulp -> fp32-identical class). Prep kernel pre-splits
//     weights into the per-block LDS layout (208B padded co stride).
//     y is NHWC fp32; BN/LIF/pool kernels re-indexed c-inner (coalesced).
// ---------------------------------------------------------------------------

#define T_STEPS 8
#define NBATCH 128

typedef __attribute__((ext_vector_type(8))) short short8;
typedef __attribute__((ext_vector_type(4))) float f32x4;

__device__ __forceinline__ uint16_t f2bf(float f) {
    uint32_t x = __float_as_uint(f);
    uint32_t r = x + 0x7FFFu + ((x >> 16) & 1u);
    return (uint16_t)(r >> 16);
}
__device__ __forceinline__ float bf2f(uint16_t h) {
    return __uint_as_float(((uint32_t)h) << 16);
}

__global__ void zero_kernel(float* p, int n) {
    int i = blockIdx.x * blockDim.x + threadIdx.x;
    if (i < n) p[i] = 0.0f;
}

// ---------------------------------------------------------------------------
// Weight prep: fp32 OIHW -> triple-bf16-split, laid out per (coblk, kchunk)
// slice exactly as the conv kernel's LDS B image:
//   slice (14976 u16): [shift 9][co16 (stride 104 u16)][split 3 (stride 32)][ci32]
// ---------------------------------------------------------------------------
template <int CIN, int COUT>
__global__ void prep_kernel(const float* __restrict__ w, uint16_t* __restrict__ wp) {
    constexpr int KC = CIN / 32;
    const int i = blockIdx.x * blockDim.x + threadIdx.x;
    if (i >= COUT * CIN * 9) return;
    const int sh = i % 9;
    const int ci = (i / 9) % CIN;
    const int co = i / (9 * CIN);
    const float v = w[i];
    const uint16_t h1 = f2bf(v);
    const float r1 = v - bf2f(h1);
    const uint16_t h2 = f2bf(r1);
    const float r2 = r1 - bf2f(h2);
    const uint16_t h3 = f2bf(r2);
    uint16_t* base = wp + (size_t)((co >> 4) * KC + (ci >> 5)) * 14976
                        + sh * 1664 + (co & 15) * 104 + (ci & 31);
    base[0] = h1;
    base[32] = h2;
    base[64] = h3;
}

// Direct 3x3 pad-1 conv (conv1 only: Cin=3, fp32 input, M=128). Writes y NHWC.
__global__ void conv3x3_kernel(const float* __restrict__ in,
                               const float* __restrict__ wgt,
                               const float* __restrict__ bias,
                               float* __restrict__ y,
                               float* __restrict__ ssum,
                               float* __restrict__ ssq,
                               int Cin, int H, int W) {
    const int m  = blockIdx.x;
    const int co = blockIdx.y;
    const int Cout = gridDim.y;
    const int HW = H * W;

    const float* wco = wgt + (size_t)co * Cin * 9;
    const float bv = bias[co];

    float lsum = 0.0f, lsq = 0.0f;

    for (int p = threadIdx.x; p < HW; p += blockDim.x) {
        const int hy = p / W;
        const int wx = p - hy * W;
        float acc = bv;
        for (int ci = 0; ci < Cin; ++ci) {
            const float* inc = in + ((size_t)m * Cin + ci) * HW;
            const float* wc = wco + ci * 9;
#pragma unroll
            for (int ky = 0; ky < 3; ++ky) {
                const int iy = hy + ky - 1;
                if (iy < 0 || iy >= H) continue;
#pragma unroll
                for (int kx = 0; kx < 3; ++kx) {
                    const int ix = wx + kx - 1;
                    if (ix < 0 || ix >= W) continue;
                    acc += inc[iy * W + ix] * wc[ky * 3 + kx];
                }
            }
        }
        y[((size_t)m * HW + p) * Cout + co] = acc;   // NHWC
        lsum += acc;
        lsq += acc * acc;
    }

    __shared__ float r1[256];
    __shared__ float r2[256];
    const int tid = threadIdx.x;
    r1[tid] = lsum;
    r2[tid] = lsq;
    __syncthreads();
    for (int s = blockDim.x >> 1; s > 0; s >>= 1) {
        if (tid < s) {
            r1[tid] += r1[tid + s];
            r2[tid] += r2[tid + s];
        }
        __syncthreads();
    }
    if (tid == 0) {
        atomicAdd(&ssum[co], r1[0]);
        atomicAdd(&ssq[co], r2[0]);
    }
}

// ---------------------------------------------------------------------------
// MFMA spike conv. in: u8 NHWC spikes [m][H*W][CIN]. y: NHWC fp32.
// grid = (M * H/ROWS, COUT/16), block 256 (4 waves).
// LDS: bf16 spike halo tile [ROWS+2][W+2][CIN] + one B slice (9 shifts x
// 16 co x 3 splits x 32 ci, co stride 208B). Each wave owns NSTRIP/4
// 16-pixel strips; 16x16x32 MFMA, 2 accs/strip for ILP.
// ---------------------------------------------------------------------------
template <int CIN, int COUT, int H, int W, int ROWS>
__global__ __launch_bounds__(256) void conv_mfma_kernel(
    const uint8_t* __restrict__ in, const uint16_t* __restrict__ wp,
    const float* __restrict__ bias, float* __restrict__ y,
    float* __restrict__ ssum, float* __restrict__ ssq)
{
    constexpr int KC = CIN / 32;
    constexpr int WP2 = W + 2;
    constexpr int HW = H * W;
    constexpr int NSTRIP = ROWS * W / 16;
    constexpr int SPW = NSTRIP / 4;          // strips per wave
    constexpr int SPIKE_U16 = (ROWS + 2) * WP2 * CIN;
    constexpr int RB = H / ROWS;
    static_assert(NSTRIP % 4 == 0, "strips");

    __shared__ __align__(16) uint16_t sp[SPIKE_U16];
    __shared__ __align__(16) uint16_t bw[14976];
    __shared__ float bn[32];

    const int tid = threadIdx.x;
    const int lane = tid & 63;
    const int wav = tid >> 6;
    const int col = lane & 15;
    const int quad = lane >> 4;

    const int m = blockIdx.x / RB;
    const int ybase = (blockIdx.x % RB) * ROWS;
    const int co0 = blockIdx.y * 16;

    // zero spike tile (halo stays 0) + bn accumulators
    for (int i = tid; i < SPIKE_U16 / 2; i += 256) ((uint32_t*)sp)[i] = 0u;
    if (tid < 32) bn[tid] = 0.0f;
    __syncthreads();

    // fill interior: u8 {0,1} -> bf16 {0,1.0} via *0x3F80
    {
        const int gy0 = (ybase - 1 < 0) ? 0 : ybase - 1;
        const int gy1 = (ybase + ROWS > H - 1) ? H - 1 : ybase + ROWS;
        const int nrows = gy1 - gy0 + 1;
        constexpr int C4 = CIN / 4;
        const int groups = nrows * W * C4;
        const uint8_t* base = in + (size_t)m * HW * CIN;
        for (int gid = tid; gid < groups; gid += 256) {
            const int ci4 = gid % C4;
            const int rest = gid / C4;
            const int gx = rest % W;
            const int gy = gy0 + rest / W;
            const uint32_t v = *(const uint32_t*)(base + (gy * W + gx) * CIN + ci4 * 4);
            const uint32_t b0 = v & 1u, b1 = (v >> 8) & 1u;
            const uint32_t b2 = (v >> 16) & 1u, b3 = v >> 24;
            const uint32_t w01 = (b0 | (b1 << 16)) * 0x3F80u;
            const uint32_t w23 = (b2 | (b3 << 16)) * 0x3F80u;
            uint32_t* d = (uint32_t*)&sp[((gy - ybase + 1) * WP2 + gx + 1) * CIN + ci4 * 4];
            d[0] = w01;
            d[1] = w23;
        }
    }

    // per-strip A base byte offsets (lane&15 = pixel-in-strip = MFMA m)
    int abase[SPW];
#pragma unroll
    for (int s = 0; s < SPW; ++s) {
        const int pxl = (wav * SPW + s) * 16 + col;
        abase[s] = ((pxl / W) * WP2 + (pxl % W)) * CIN * 2 + quad * 16;
    }

    f32x4 acc[SPW][2];
#pragma unroll
    for (int s = 0; s < SPW; ++s) {
        acc[s][0] = (f32x4)0.0f;
        acc[s][1] = (f32x4)0.0f;
    }

    const uint16_t* wpb = wp + (size_t)blockIdx.y * KC * 14976;

#pragma unroll
    for (int kc = 0; kc < KC; ++kc) {
        __syncthreads();   // LDS B free (spike fill done / prev reads done)
        {
            const float4* src = (const float4*)(wpb + kc * 14976);
            float4* dst = (float4*)bw;
            for (int i = tid; i < 29952 / 16; i += 256) dst[i] = src[i];
        }
        __syncthreads();
#pragma unroll
        for (int sh = 0; sh < 9; ++sh) {
            const int dy = sh / 3, dx = sh % 3;
            const int bidx = sh * 1664 + col * 104 + quad * 8;
            const short8 b0 = *(const short8*)&bw[bidx];
            const short8 b1 = *(const short8*)&bw[bidx + 32];
            const short8 b2 = *(const short8*)&bw[bidx + 64];
#pragma unroll
            for (int s = 0; s < SPW; ++s) {
                const int aoff = abase[s] + (dy * WP2 + dx) * CIN * 2 + kc * 64;
                const short8 a = *(const short8*)((const uint8_t*)sp + aoff);
                f32x4 t = acc[s][sh & 1];
                t = __builtin_amdgcn_mfma_f32_16x16x32_bf16(a, b0, t, 0, 0, 0);
                t = __builtin_amdgcn_mfma_f32_16x16x32_bf16(a, b1, t, 0, 0, 0);
                t = __builtin_amdgcn_mfma_f32_16x16x32_bf16(a, b2, t, 0, 0, 0);
                acc[s][sh & 1] = t;
            }
        }
    }

    // epilogue: bias, NHWC y store (D: col=lane&15=co, row=quad*4+r=px), BN stats
    const float bv = bias[co0 + col];
#pragma unroll
    for (int s = 0; s < SPW; ++s) {
        const int stripid = wav * SPW + s;
        float sum = 0.0f, sq = 0.0f;
#pragma unroll
        for (int r = 0; r < 4; ++r) {
            const float v = acc[s][0][r] + acc[s][1][r] + bv;
            const int px = ybase * W + stripid * 16 + quad * 4 + r;
            y[((size_t)m * HW + px) * COUT + co0 + col] = v;
            sum += v;
            sq += v * v;
        }
        sum += __shfl_xor(sum, 16, 64);
        sum += __shfl_xor(sum, 32, 64);
        sq += __shfl_xor(sq, 16, 64);
        sq += __shfl_xor(sq, 32, 64);
        if (quad == 0) {
            atomicAdd(&bn[col], sum);
            atomicAdd(&bn[16 + col], sq);
        }
    }
    __syncthreads();
    if (tid < 16) atomicAdd(&ssum[co0 + tid], bn[tid]);
    else if (tid < 32) atomicAdd(&ssq[co0 + tid - 16], bn[tid]);
}

// Layer-1 BN+LIF: y NHWC [N][HW][C] fp32 (same for every t) -> spikes u8 NHWC.
__global__ void bnlif1_kernel(const float* __restrict__ y,
                              const float* __restrict__ ssum,
                              const float* __restrict__ ssq,
                              const float* __restrict__ g,
                              const float* __restrict__ be,
                              uint8_t* __restrict__ s,
                              int C, int HW, float invM) {
    const size_t total = (size_t)NBATCH * C * HW;
    const size_t i = (size_t)blockIdx.x * blockDim.x + threadIdx.x;
    if (i >= total) return;
    const int c = (int)(i % C);
    const float m = ssum[c] * invM;
    const float var = ssq[c] * invM - m * m;
    const float inv = g[c] / sqrtf(var + 1e-5f);
    const float z = y[i] * inv + (be[c] - m * inv);
    float v = 0.0f;
#pragma unroll
    for (int t = 0; t < T_STEPS; ++t) {
        v += (z - v) * 0.5f;
        const float sp = (v >= 1.0f) ? 1.0f : 0.0f;
        s[(size_t)t * total + i] = (uint8_t)sp;
        v *= (1.0f - sp);
    }
}

// BN+LIF (no pool): y NHWC [T*N][HW][C] -> spikes u8 NHWC same layout.
__global__ void bnlif_kernel(const float* __restrict__ y,
                             const float* __restrict__ ssum,
                             const float* __restrict__ ssq,
                             const float* __restrict__ g,
                             const float* __restrict__ be,
                             uint8_t* __restrict__ s,
                             int C, int HW, float invM) {
    const size_t total = (size_t)NBATCH * C * HW;
    const size_t i = (size_t)blockIdx.x * blockDim.x + threadIdx.x;
    if (i >= total) return;
    const int c = (int)(i % C);
    const float m = ssum[c] * invM;
    const float var = ssq[c] * invM - m * m;
    const float inv = g[c] / sqrtf(var + 1e-5f);
    const float sh = be[c] - m * inv;
    float v = 0.0f;
#pragma unroll
    for (int t = 0; t < T_STEPS; ++t) {
        const float z = y[(size_t)t * total + i] * inv + sh;
        v += (z - v) * 0.5f;
        const float sp = (v >= 1.0f) ? 1.0f : 0.0f;
        s[(size_t)t * total + i] = (uint8_t)sp;
        v *= (1.0f - sp);
    }
}

// BN+LIF + 2x2 max-pool. y NHWC [T*N][H][W][C] -> pooled spikes u8 NHWC.
__global__ void bnlifpool_kernel(const float* __restrict__ y,
                                 const float* __restrict__ ssum,
                                 const float* __restrict__ ssq,
                                 const float* __restrict__ g,
                                 const float* __restrict__ be,
                                 uint8_t* __restrict__ p,
                                 int C, int H, int W, float invM) {
    const int PH = H >> 1, PW = W >> 1;
    const size_t ptotal = (size_t)NBATCH * C * PH * PW;
    const size_t i = (size_t)blockIdx.x * blockDim.x + threadIdx.x;
    if (i >= ptotal) return;
    const int c = (int)(i % C);
    const int pw = (int)((i / C) % PW);
    const int ph = (int)((i / ((size_t)C * PW)) % PH);
    const int n = (int)(i / ((size_t)C * PW * PH));

    const float m = ssum[c] * invM;
    const float var = ssq[c] * invM - m * m;
    const float inv = g[c] / sqrtf(var + 1e-5f);
    const float sh = be[c] - m * inv;

    const size_t base = (((size_t)n * H + 2 * ph) * W + 2 * pw) * C + c;
    const size_t tstride = (size_t)NBATCH * H * W * C;

    float v00 = 0.f, v01 = 0.f, v10 = 0.f, v11 = 0.f;
#pragma unroll
    for (int t = 0; t < T_STEPS; ++t) {
        const float* yt = y + (size_t)t * tstride + base;
        const float z00 = yt[0] * inv + sh;
        const float z01 = yt[C] * inv + sh;
        const float z10 = yt[(size_t)W * C] * inv + sh;
        const float z11 = yt[(size_t)W * C + C] * inv + sh;
        v00 += (z00 - v00) * 0.5f;
        v01 += (z01 - v01) * 0.5f;
        v10 += (z10 - v10) * 0.5f;
        v11 += (z11 - v11) * 0.5f;
        const float s00 = (v00 >= 1.0f) ? 1.0f : 0.0f;
        const float s01 = (v01 >= 1.0f) ? 1.0f : 0.0f;
        const float s10 = (v10 >= 1.0f) ? 1.0f : 0.0f;
        const float s11 = (v11 >= 1.0f) ? 1.0f : 0.0f;
        v00 *= (1.0f - s00);
        v01 *= (1.0f - s01);
        v10 *= (1.0f - s10);
        v11 *= (1.0f - s11);
        const float mx = fmaxf(fmaxf(s00, s01), fmaxf(s10, s11));
        p[(size_t)t * ptotal + i] = (uint8_t)mx;
    }
}

// fc1: f u8 NHWC [T*N][16px][128c]; reference feature order is c*16+px.
__global__ void fc1_kernel(const uint8_t* __restrict__ f,
                           const float* __restrict__ w,
                           const float* __restrict__ b,
                           float* __restrict__ h) {
    __shared__ float fs[2048];
    const int r = blockIdx.x;
    const uint8_t* fr = f + (size_t)r * 2048;
    for (int i = threadIdx.x; i < 2048; i += blockDim.x)
        fs[(i & 127) * 16 + (i >> 7)] = (float)fr[i];   // [c][px] NCHW order
    __syncthreads();
    const int o = threadIdx.x;  // blockDim = 128
    const float4* fv = (const float4*)fs;
    const float4* wv = (const float4*)(w + (size_t)o * 2048);
    float acc = b[o];
    for (int i = 0; i < 512; ++i) {
        const float4 a = fv[i];
        const float4 ww = wv[i];
        acc += a.x * ww.x + a.y * ww.y + a.z * ww.z + a.w * ww.w;
    }
    h[(size_t)r * 128 + o] = acc;
}

// LIF over T for fc1 outputs: h [T, NF] -> spikes uint8 same layout.
__global__ void lif_fc_kernel(const float* __restrict__ h,
                              uint8_t* __restrict__ s, int NF) {
    const int i = blockIdx.x * blockDim.x + threadIdx.x;
    if (i >= NF) return;
    float v = 0.0f;
#pragma unroll
    for (int t = 0; t < T_STEPS; ++t) {
        const float z = h[(size_t)t * NF + i];
        v += (z - v) * 0.5f;
        const float sp = (v >= 1.0f) ? 1.0f : 0.0f;
        s[(size_t)t * NF + i] = (uint8_t)sp;
        v *= (1.0f - sp);
    }
}

// fc2 + LIF + mean over T. sh [T,N,128] uint8, w [10,128]. out [N,10].
__global__ void fc2_kernel(const uint8_t* __restrict__ sh,
                           const float* __restrict__ w,
                           const float* __restrict__ b,
                           float* __restrict__ out) {
    const int i = blockIdx.x * blockDim.x + threadIdx.x;
    if (i >= NBATCH * 10) return;
    const int k = i % 10;
    const int n = i / 10;
    float v = 0.0f, acc = 0.0f;
    for (int t = 0; t < T_STEPS; ++t) {
        const uint8_t* row = sh + ((size_t)t * NBATCH + n) * 128;
        float z = b[k];
        for (int o = 0; o < 128; ++o)
            z += (float)row[o] * w[k * 128 + o];
        v += (z - v) * 0.5f;
        const float sp = (v >= 1.0f) ? 1.0f : 0.0f;
        acc += sp;
        v *= (1.0f - sp);
    }
    out[i] = acc * (1.0f / T_STEPS);
}

extern "C" void kernel_launch(void* const* d_in, const int* in_sizes, int n_in,
                              void* d_out, int out_size, void* d_ws, size_t ws_size,
                              hipStream_t stream) {
    const float* x   = (const float*)d_in[0];
    const float* W1  = (const float*)d_in[1];
    const float* Bi1 = (const float*)d_in[2];
    const float* G1  = (const float*)d_in[3];
    const float* BE1 = (const float*)d_in[4];
    const float* W2  = (const float*)d_in[5];
    const float* Bi2 = (const float*)d_in[6];
    const float* G2  = (const float*)d_in[7];
    const float* BE2 = (const float*)d_in[8];
    const float* W3  = (const float*)d_in[9];
    const float* Bi3 = (const float*)d_in[10];
    const float* G3  = (const float*)d_in[11];
    const float* BE3 = (const float*)d_in[12];
    const float* W4  = (const float*)d_in[13];
    const float* Bi4 = (const float*)d_in[14];
    const float* G4  = (const float*)d_in[15];
    const float* BE4 = (const float*)d_in[16];
    const float* W5  = (const float*)d_in[17];
    const float* Bi5 = (const float*)d_in[18];
    const float* G5  = (const float*)d_in[19];
    const float* BE5 = (const float*)d_in[20];
    const float* W6  = (const float*)d_in[21];
    const float* Bi6 = (const float*)d_in[22];
    const float* G6  = (const float*)d_in[23];
    const float* BE6 = (const float*)d_in[24];
    const float* FC1W = (const float*)d_in[25];
    const float* FC1B = (const float*)d_in[26];
    const float* FC2W = (const float*)d_in[27];
    const float* FC2B = (const float*)d_in[28];

    // workspace layout
    uint8_t* ws = (uint8_t*)d_ws;
    float*    Y     = (float*)ws;                       // 134,217,728 B (max y: layer2)
    uint8_t*  A     = ws + 134217728;                   // 33,554,432 B spike ping (u8 NHWC)
    uint8_t*  Bb    = A + 33554432;                     //  8,388,608 B spike pong
    float*    stats = (float*)(Bb + 8388608);           //  6,144 B used (8 KB reserved)
    float*    h     = (float*)((uint8_t*)stats + 8192); //  524,288 B fc1 out
    uint8_t*  shb   = (uint8_t*)h + 524288;             //  131,072 B fc1 spikes
    uint16_t* Wp    = (uint16_t*)(shb + 131072);        //  1,857,024 B prepped weights
    uint16_t* Wp2p = Wp;                 //  2 slices
    uint16_t* Wp3p = Wp + 29952;         //  4 slices
    uint16_t* Wp4p = Wp + 89856;         //  8 slices
    uint16_t* Wp5p = Wp + 209664;        // 16 slices
    uint16_t* Wp6p = Wp + 449280;        // 32 slices

    zero_kernel<<<(1536 + 255) / 256, 256, 0, stream>>>(stats, 1536);

    // weight prep (all layers)
    prep_kernel<32, 32><<<(9216 + 255) / 256, 256, 0, stream>>>(W2, Wp2p);
    prep_kernel<32, 64><<<(18432 + 255) / 256, 256, 0, stream>>>(W3, Wp3p);
    prep_kernel<64, 64><<<(36864 + 255) / 256, 256, 0, stream>>>(W4, Wp4p);
    prep_kernel<64, 128><<<(73728 + 255) / 256, 256, 0, stream>>>(W5, Wp5p);
    prep_kernel<128, 128><<<(147456 + 255) / 256, 256, 0, stream>>>(W6, Wp6p);

    const int TN = T_STEPS * NBATCH;  // 1024

    // ---- layer 1: conv(3->32) over N only (T-invariant), BN, LIF ----
    {
        dim3 g(NBATCH, 32);
        conv3x3_kernel<<<g, 256, 0, stream>>>(x, W1, Bi1, Y,
                                              stats + 0, stats + 128, 3, 32, 32);
        const int total = NBATCH * 32 * 1024;
        bnlif1_kernel<<<total / 256, 256, 0, stream>>>(Y, stats + 0, stats + 128,
                                                       G1, BE1, A, 32, 1024,
                                                       1.0f / 131072.0f);
    }
    // ---- layer 2: conv(32->32) 32x32, BN, LIF, pool -> Bb ----
    {
        conv_mfma_kernel<32, 32, 32, 32, 8><<<dim3(TN * 4, 2), 256, 0, stream>>>(
            A, Wp2p, Bi2, Y, stats + 256, stats + 384);
        const int ptotal = NBATCH * 32 * 256;
        bnlifpool_kernel<<<ptotal / 256, 256, 0, stream>>>(Y, stats + 256, stats + 384,
                                                           G2, BE2, Bb, 32, 32, 32,
                                                           1.0f / (1024.0f * 1024.0f));
    }
    // ---- layer 3: conv(32->64) 16x16, BN, LIF -> A ----
    {
        conv_mfma_kernel<32, 64, 16, 16, 16><<<dim3(TN, 4), 256, 0, stream>>>(
            Bb, Wp3p, Bi3, Y, stats + 512, stats + 640);
        const int total = NBATCH * 64 * 256;
        bnlif_kernel<<<total / 256, 256, 0, stream>>>(Y, stats + 512, stats + 640,
                                                      G3, BE3, A, 64, 256,
                                                      1.0f / (1024.0f * 256.0f));
    }
    // ---- layer 4: conv(64->64) 16x16, BN, LIF, pool -> Bb ----
    {
        conv_mfma_kernel<64, 64, 16, 16, 8><<<dim3(TN * 2, 4), 256, 0, stream>>>(
            A, Wp4p, Bi4, Y, stats + 768, stats + 896);
        const int ptotal = NBATCH * 64 * 64;
        bnlifpool_kernel<<<ptotal / 256, 256, 0, stream>>>(Y, stats + 768, stats + 896,
                                                           G4, BE4, Bb, 64, 16, 16,
                                                           1.0f / (1024.0f * 256.0f));
    }
    // ---- layer 5: conv(64->128) 8x8, BN, LIF -> A ----
    {
        conv_mfma_kernel<64, 128, 8, 8, 8><<<dim3(TN, 8), 256, 0, stream>>>(
            Bb, Wp5p, Bi5, Y, stats + 1024, stats + 1152);
        const int total = NBATCH * 128 * 64;
        bnlif_kernel<<<total / 256, 256, 0, stream>>>(Y, stats + 1024, stats + 1152,
                                                      G5, BE5, A, 128, 64,
                                                      1.0f / (1024.0f * 64.0f));
    }
    // ---- layer 6: conv(128->128) 8x8, BN, LIF, pool -> Bb ----
    {
        conv_mfma_kernel<128, 128, 8, 8, 8><<<dim3(TN, 8), 256, 0, stream>>>(
            A, Wp6p, Bi6, Y, stats + 1280, stats + 1408);
        const int ptotal = NBATCH * 128 * 16;
        bnlifpool_kernel<<<ptotal / 256, 256, 0, stream>>>(Y, stats + 1280, stats + 1408,
                                                           G6, BE6, Bb, 128, 8, 8,
                                                           1.0f / (1024.0f * 64.0f));
    }
    // ---- fc1 (2048->128) + LIF ----
    fc1_kernel<<<TN, 128, 0, stream>>>(Bb, FC1W, FC1B, h);
    lif_fc_kernel<<<(NBATCH * 128 + 255) / 256, 256, 0, stream>>>(h, shb, NBATCH * 128);
    // ---- fc2 (128->10) + LIF + mean ----
    fc2_kernel<<<(NBATCH * 10 + 255) / 256, 256, 0, stream>>>(shb, FC2W, FC2B, (float*)d_out);
}